// Round 8
// baseline (386.435 us; speedup 1.0000x reference)
//
#include <hip/hip_runtime.h>
#include <hip/hip_cooperative_groups.h>
#include <math.h>

namespace cg = cooperative_groups;

#define KBINS 8192
#define DDIM  16384      // 2*K
#define HID   2048
#define LASTROW 16384    // the t row of W1 (row index D)

#define NCH1 1024        // mv1 chunks (16 rows each)
#define NCH2 256         // mv2 chunks (8 rows each)

static constexpr float SQRT2_F  = 1.4142135623730951f;
static constexpr float INVSQ2PI = 0.3989422804014327f;   // 1/sqrt(2*pi)

// Branch-free erf approximation (A&S 7.1.26), |err| < 1.5e-7.
__device__ __forceinline__ float fast_erff(float x) {
    float ax = fabsf(x);
    float t  = 1.0f / fmaf(0.3275911f, ax, 1.0f);
    float p  = t * (0.254829592f +
               t * (-0.284496736f +
               t * (1.421413741f +
               t * (-1.453152027f +
               t * 1.061405429f))));
    float r = 1.0f - p * __expf(-ax * ax);
    return copysignf(r, x);
}

// ================= Fused cooperative kernel (block-stride phases) =================
__global__ void __launch_bounds__(256)
fused(const float* __restrict__ mu, const float* __restrict__ t,
      const float* __restrict__ gamma, const float* __restrict__ W1,
      const float* __restrict__ b1, const float* __restrict__ W2,
      const float* __restrict__ b2, float* __restrict__ out,
      float* __restrict__ part1, float* __restrict__ h,
      float* __restrict__ part2) {
    cg::grid_group grid = cg::this_grid();
    const int tid = threadIdx.x;
    const int G   = gridDim.x;

    __shared__ float a_s[16];
    __shared__ float red[16][17];
    __shared__ float hs8[8];
    __shared__ float s01[2][8];
    __shared__ float sA[8], sB[8], sCf[8], sEr[8];

    // ---- P1: part1[ch][c] = sum_{k<16} mu[16ch+k]*W1[16ch+k][c] ----
    for (int ch = blockIdx.x; ch < NCH1; ch += G) {
        int r0 = ch * 16;
        if (tid < 16) a_s[tid] = mu[r0 + tid];
        __syncthreads();
        int c0 = tid * 4;
        float4 acc0 = {0.f, 0.f, 0.f, 0.f};
        float4 acc1 = {0.f, 0.f, 0.f, 0.f};
        const float* wp = W1 + (size_t)r0 * HID;
#pragma unroll
        for (int k = 0; k < 16; ++k) {
            float a = a_s[k];
            const float4 w0 = *reinterpret_cast<const float4*>(wp + (size_t)k * HID + c0);
            const float4 w1 = *reinterpret_cast<const float4*>(wp + (size_t)k * HID + c0 + 1024);
            acc0.x += a * w0.x; acc0.y += a * w0.y; acc0.z += a * w0.z; acc0.w += a * w0.w;
            acc1.x += a * w1.x; acc1.y += a * w1.y; acc1.z += a * w1.z; acc1.w += a * w1.w;
        }
        float* pp = part1 + (size_t)ch * HID;
        *reinterpret_cast<float4*>(pp + c0)        = acc0;
        *reinterpret_cast<float4*>(pp + c0 + 1024) = acc1;
        __syncthreads();
    }
    grid.sync();

    // ---- P2: h[c] = leaky(b1 + t*W1[D] + sum_ch part1), 128 tiles x 16 cols ----
    for (int cb = blockIdx.x; cb < 128; cb += G) {
        int c0    = cb * 16;
        int col_l = tid & 15;
        int sub   = tid >> 4;                   // 0..15
        float s = 0.f;
        const float* p = part1 + c0 + col_l;
#pragma unroll 8
        for (int m = 0; m < 64; ++m)
            s += p[(size_t)(sub + (m << 4)) * HID];
        red[sub][col_l] = s;
        __syncthreads();
        if (tid < 16) {
            int c = c0 + tid;
            float v = b1[c] + t[0] * W1[(size_t)LASTROW * HID + c];
#pragma unroll
            for (int q = 0; q < 16; ++q) v += red[q][tid];
            h[c] = (v >= 0.f) ? v : 0.01f * v;
        }
        __syncthreads();
    }
    grid.sync();

    // ---- P3: part2[ch][c] = sum_{k<8} h[8ch+k]*W2[8ch+k][c] ----
    for (int cq = blockIdx.x; cq < NCH1; cq += G) {   // 256 chunks x 4 col-quarters
        int ch    = cq >> 2;
        int quar  = cq & 3;
        int r0    = ch * 8;
        int cbase = quar * 4096;
        if (tid < 8) hs8[tid] = h[r0 + tid];
        __syncthreads();
        float4 acc[4];
#pragma unroll
        for (int q = 0; q < 4; ++q) acc[q] = {0.f, 0.f, 0.f, 0.f};
        const float* wp = W2 + (size_t)r0 * DDIM + cbase + tid * 4;
#pragma unroll
        for (int k = 0; k < 8; ++k) {
            float a = hs8[k];
            const float* wr = wp + (size_t)k * DDIM;
#pragma unroll
            for (int q = 0; q < 4; ++q) {
                const float4 w = *reinterpret_cast<const float4*>(wr + q * 1024);
                acc[q].x += a * w.x; acc[q].y += a * w.y;
                acc[q].z += a * w.z; acc[q].w += a * w.w;
            }
        }
        float* pp = part2 + (size_t)ch * DDIM + cbase + tid * 4;
#pragma unroll
        for (int q = 0; q < 4; ++q)
            *reinterpret_cast<float4*>(pp + q * 1024) = acc[q];
        __syncthreads();
    }
    grid.sync();

    // ---- P4 + P5: per 8 rows, scalars then cdf rows ----
    for (int rb = blockIdx.x; rb < 1024; rb += G) {
        int r0 = rb * 8;
        {
            int col_l = tid & 7;
            int half  = (tid >> 3) & 1;
            int sub   = tid >> 4;                   // 0..15
            int c     = r0 + col_l + half * KBINS;
            float s = 0.f;
            const float* p = part2 + c;
#pragma unroll 8
            for (int m = 0; m < 16; ++m)
                s += p[(size_t)(sub + (m << 4)) * DDIM];
            red[sub][half * 8 + col_l] = s;
            __syncthreads();
            if (tid < 16) {
                int hlf = tid >> 3, cl = tid & 7;
                float v = b2[r0 + cl + hlf * KBINS];
#pragma unroll
                for (int q = 0; q < 16; ++q) v += red[q][tid];
                s01[hlf][cl] = v;
            }
            __syncthreads();
            if (tid < 8) {
                float s0 = s01[0][tid];
                float s1 = s01[1][tid];
                float g  = gamma[0];
                float pe = 1.0f / (1.0f - g);
                float pm = g - pe;
                bool use_nn = (t[0] >= 1e-10f);
                float mval = use_nn ? powf(mu[r0 + tid], pm) * powf(s0, pe) : 0.0f;
                float invs = use_nn ? powf(1.0f - g, 0.5f) * expf(-0.5f * s1) : 1.0f;
                const float sc = 2.0f / 8191.0f;
                float A    = sc * invs;
                sA[tid]  = A;
                sB[tid]  = (-1.0f / 8191.0f - mval) * invs;
                sCf[tid] = INVSQ2PI * A;
                float z = (8190.0f / 8191.0f - mval) * invs * (1.0f / SQRT2_F);
                sEr[tid] = 0.5f * (1.0f - fast_erff(z));
            }
            __syncthreads();
        }
#pragma unroll 2
        for (int rr = 0; rr < 8; ++rr) {
            int i = r0 + rr;
            float A    = sA[rr];
            float B    = sB[rr];
            float coef = sCf[rr];
            float* orow = out + (size_t)i * KBINS;
#pragma unroll
            for (int it = 0; it < 8; ++it) {
                int j0 = it * 1024 + tid * 4;
                float4 r;
                if (j0 < 4096) {
                    float u0 = fmaf((float)j0, A, B);
                    float u1 = u0 + A;
                    float u2 = u1 + A;
                    float u3 = u2 + A;
                    r.x = coef * __expf(-0.5f * u0 * u0);
                    r.y = coef * __expf(-0.5f * u1 * u1);
                    r.z = coef * __expf(-0.5f * u2 * u2);
                    r.w = coef * __expf(-0.5f * u3 * u3);
                } else if (j0 == 4096) {
                    r.x = sEr[rr];
                    r.y = r.z = r.w = 0.f;
                } else {
                    r.x = r.y = r.z = r.w = 0.f;
                }
                *reinterpret_cast<float4*>(orow + j0) = r;
            }
        }
        __syncthreads();
    }
}

// ================= Fallback pipeline (proven R6, 144 us) =================
__global__ void __launch_bounds__(256)
mv1_partial(const float* __restrict__ mu, const float* __restrict__ W1,
            float* __restrict__ part1) {
    __shared__ float a_s[16];
    int r0 = blockIdx.x * 16;
    if (threadIdx.x < 16) a_s[threadIdx.x] = mu[r0 + threadIdx.x];
    __syncthreads();
    int c0 = threadIdx.x * 4;
    float4 acc0 = {0.f, 0.f, 0.f, 0.f};
    float4 acc1 = {0.f, 0.f, 0.f, 0.f};
    const float* wp = W1 + (size_t)r0 * HID;
#pragma unroll
    for (int k = 0; k < 16; ++k) {
        float a = a_s[k];
        const float4 w0 = *reinterpret_cast<const float4*>(wp + (size_t)k * HID + c0);
        const float4 w1 = *reinterpret_cast<const float4*>(wp + (size_t)k * HID + c0 + 1024);
        acc0.x += a * w0.x; acc0.y += a * w0.y; acc0.z += a * w0.z; acc0.w += a * w0.w;
        acc1.x += a * w1.x; acc1.y += a * w1.y; acc1.z += a * w1.z; acc1.w += a * w1.w;
    }
    float* pp = part1 + (size_t)blockIdx.x * HID;
    *reinterpret_cast<float4*>(pp + c0)        = acc0;
    *reinterpret_cast<float4*>(pp + c0 + 1024) = acc1;
}

__global__ void __launch_bounds__(256)
mv2h(const float* __restrict__ part1, const float* __restrict__ b1,
     const float* __restrict__ W1, const float* __restrict__ t,
     const float* __restrict__ W2, float* __restrict__ part2) {
    __shared__ float red[32][8];
    __shared__ float hs[8];
    int r0    = blockIdx.y * 8;
    int cbase = blockIdx.x * 8192;
    int col_l = threadIdx.x & 7;
    int sub   = threadIdx.x >> 3;
    {
        float s = 0.f;
        const float* p = part1 + r0 + col_l;
#pragma unroll 8
        for (int m = 0; m < 32; ++m)
            s += p[(size_t)(sub + (m << 5)) * HID];
        red[sub][col_l] = s;
    }
    __syncthreads();
    if (threadIdx.x < 8) {
        int r = r0 + threadIdx.x;
        float v = b1[r] + t[0] * W1[(size_t)LASTROW * HID + r];
#pragma unroll
        for (int p = 0; p < 32; ++p) v += red[p][threadIdx.x];
        hs[threadIdx.x] = (v >= 0.f) ? v : 0.01f * v;
    }
    __syncthreads();
    int c0 = threadIdx.x * 4;
    float4 acc[8];
#pragma unroll
    for (int q = 0; q < 8; ++q) acc[q] = {0.f, 0.f, 0.f, 0.f};
    const float* wp = W2 + (size_t)r0 * DDIM + cbase + c0;
#pragma unroll 2
    for (int k = 0; k < 8; ++k) {
        float a = hs[k];
        const float* wr = wp + (size_t)k * DDIM;
#pragma unroll
        for (int q = 0; q < 8; ++q) {
            const float4 w = *reinterpret_cast<const float4*>(wr + q * 1024);
            acc[q].x += a * w.x; acc[q].y += a * w.y;
            acc[q].z += a * w.z; acc[q].w += a * w.w;
        }
    }
    float* pp = part2 + (size_t)blockIdx.y * DDIM + cbase + c0;
#pragma unroll
    for (int q = 0; q < 8; ++q)
        *reinterpret_cast<float4*>(pp + q * 1024) = acc[q];
}

__global__ void __launch_bounds__(256)
scalars(const float* __restrict__ part2, const float* __restrict__ b2,
        const float* __restrict__ mu, const float* __restrict__ t,
        const float* __restrict__ gamma,
        float* __restrict__ mu_x, float* __restrict__ sigma_x) {
    __shared__ float red0[8][32];
    __shared__ float red1[8][32];
    int col_l = threadIdx.x & 31;
    int sub   = threadIdx.x >> 5;
    int c     = blockIdx.x * 32 + col_l;
    float s0 = 0.f, s1 = 0.f;
    const float* p0 = part2 + c;
    const float* p1 = part2 + c + KBINS;
#pragma unroll 8
    for (int m = 0; m < 32; ++m) {
        size_t off = (size_t)(sub + (m << 3)) * DDIM;
        s0 += p0[off];
        s1 += p1[off];
    }
    red0[sub][col_l] = s0;
    red1[sub][col_l] = s1;
    __syncthreads();
    if (threadIdx.x < 32) {
        int cc = blockIdx.x * 32 + threadIdx.x;
        float v0 = b2[cc];
        float v1 = b2[cc + KBINS];
#pragma unroll
        for (int p = 0; p < 8; ++p) { v0 += red0[p][threadIdx.x]; v1 += red1[p][threadIdx.x]; }
        float g  = gamma[0];
        float pe = 1.0f / (1.0f - g);
        float pm = g - pe;
        bool use_nn = (t[0] >= 1e-10f);
        float mx = powf(mu[cc], pm) * powf(v0, pe);
        float sx = powf(1.0f - g, -0.5f) * expf(0.5f * v1);
        mu_x[cc]    = use_nn ? mx : 0.0f;
        sigma_x[cc] = use_nn ? sx : 1.0f;
    }
}

__global__ void __launch_bounds__(256)
cdf_row(const float* __restrict__ mu_x, const float* __restrict__ sigma_x,
        float* __restrict__ out) {
    int tid = threadIdx.x;
    for (int rr = 0; rr < 2; ++rr) {
        int i = blockIdx.x * 2 + rr;
        float m    = mu_x[i];
        float invs = 1.0f / sigma_x[i];
        const float sc = 2.0f / 8191.0f;
        float A    = sc * invs;
        float B    = (-1.0f / 8191.0f - m) * invs;
        float coef = INVSQ2PI * A;
        float* orow = out + (size_t)i * KBINS;
#pragma unroll
        for (int it = 0; it < 8; ++it) {
            int j0 = it * 1024 + tid * 4;
            float4 r;
            if (j0 < 4096) {
                float u0 = fmaf((float)j0, A, B);
                float u1 = u0 + A;
                float u2 = u1 + A;
                float u3 = u2 + A;
                r.x = coef * __expf(-0.5f * u0 * u0);
                r.y = coef * __expf(-0.5f * u1 * u1);
                r.z = coef * __expf(-0.5f * u2 * u2);
                r.w = coef * __expf(-0.5f * u3 * u3);
            } else if (j0 == 4096) {
                float z = (8190.0f / 8191.0f - m) * invs * (1.0f / SQRT2_F);
                r.x = 0.5f * (1.0f - fast_erff(z));
                r.y = r.z = r.w = 0.f;
            } else {
                r.x = r.y = r.z = r.w = 0.f;
            }
            *reinterpret_cast<float4*>(orow + j0) = r;
        }
    }
}

extern "C" void kernel_launch(void* const* d_in, const int* in_sizes, int n_in,
                              void* d_out, int out_size, void* d_ws, size_t ws_size,
                              hipStream_t stream) {
    const float* mu    = (const float*)d_in[0];
    const float* t     = (const float*)d_in[1];
    const float* gamma = (const float*)d_in[2];
    const float* W1    = (const float*)d_in[3];
    const float* b1    = (const float*)d_in[4];
    const float* W2    = (const float*)d_in[5];
    const float* b2    = (const float*)d_in[6];
    float* out = (float*)d_out;

    float* ws    = (float*)d_ws;
    float* part1 = ws;                               // 1024*2048 = 8 MB
    float* h     = part1 + (size_t)NCH1 * HID;       // 2048
    float* part2 = h + HID;                          // 256*16384 = 16 MB
    float* mu_x  = part2 + (size_t)NCH2 * DDIM;      // 8192
    float* sig_x = mu_x + KBINS;                     // 8192

    // Host-side queries: cheap, deterministic, capture-safe (not stream ops).
    int dev = 0;
    (void)hipGetDevice(&dev);
    int coop = 0, ncu = 0, nb = 0;
    (void)hipDeviceGetAttribute(&coop, hipDeviceAttributeCooperativeLaunch, dev);
    (void)hipDeviceGetAttribute(&ncu, hipDeviceAttributeMultiprocessorCount, dev);
    (void)hipOccupancyMaxActiveBlocksPerMultiprocessor(&nb, (const void*)fused, 256, 0);

    hipError_t err = hipErrorUnknown;
    long maxg = (long)nb * (long)ncu;
    int G = (int)((maxg > 1024) ? 1024 : maxg);
    if (coop && G >= 256) {
        void* args[] = {(void*)&mu, (void*)&t, (void*)&gamma, (void*)&W1, (void*)&b1,
                        (void*)&W2, (void*)&b2, (void*)&out, (void*)&part1, (void*)&h,
                        (void*)&part2};
        err = hipLaunchCooperativeKernel((const void*)fused, dim3(G), dim3(256), args, 0, stream);
    }
    if (err != hipSuccess) {
        (void)hipGetLastError();   // clear error state
        mv1_partial<<<dim3(NCH1),     dim3(256), 0, stream>>>(mu, W1, part1);
        mv2h       <<<dim3(2, NCH2),  dim3(256), 0, stream>>>(part1, b1, W1, t, W2, part2);
        scalars    <<<dim3(256),      dim3(256), 0, stream>>>(part2, b2, mu, t, gamma, mu_x, sig_x);
        cdf_row    <<<dim3(4096),     dim3(256), 0, stream>>>(mu_x, sig_x, out);
    }
}